// Round 3
// baseline (67.722 us; speedup 1.0000x reference)
//
#include <hip/hip_runtime.h>

constexpr int DIN  = 256;
constexpr int DOUT = 32;
constexpr int ET   = 32;    // entities per block in k1
constexpr int Z4   = 50;    // float4 zero-stores per thread in k1

typedef float vfloat4 __attribute__((ext_vector_type(4)));

__device__ __forceinline__ void gload_lds16(const float* g, float* l) {
    __builtin_amdgcn_global_load_lds(
        (const __attribute__((address_space(1))) void*)g,
        (__attribute__((address_space(3))) void*)l, 16, 0, 0);
}

// ---------------- k1: zero out-slice (nontemporal, fire-and-forget) + GEMM -> ws
__global__ __launch_bounds__(256, 2)
void k1_zero_gemm(const float* __restrict__ emb,
                  const float* __restrict__ weight,
                  const float* __restrict__ bias,
                  float* __restrict__ out,
                  float* __restrict__ ws,
                  int nent, int zTotal4)
{
    __shared__ float s_emb[ET * DIN];   // 32 KB; 16B granules XOR-swizzled by row&7
    __shared__ float s_w[DIN * DOUT];   // 32 KB; linear

    const int tid  = threadIdx.x;
    const int lane = tid & 63;
    const int w    = tid >> 6;      // wave 0..3
    const int eg   = tid & 31;      // entity row 0..31
    const int og   = tid >> 5;      // out group 0..7 (4 cols each)
    const int eb   = blockIdx.x * ET;

    // stage emb: one row (64 granules) per wave-iteration; source pre-swizzled
    #pragma unroll
    for (int j = 0; j < 8; ++j) {
        const int row = w * 8 + j;
        int er = eb + row; if (er >= nent) er = nent - 1;
        const int gsrc = lane ^ (row & 7);
        gload_lds16(emb + (size_t)er * DIN + gsrc * 4, &s_emb[row * DIN]);
    }
    // stage W: 2048 granules, linear
    #pragma unroll
    for (int j = 0; j < 8; ++j) {
        const int gbase = (w * 8 + j) * 64;
        gload_lds16(weight + (size_t)(gbase + lane) * 4, &s_w[gbase * 4]);
    }

    // zero batch A: 25 stores queued BEHIND the 16 loads
    const size_t zbase = (size_t)blockIdx.x * (Z4 * 256) + tid;
    vfloat4* outv = (vfloat4*)out;
    const vfloat4 z4 = {0.f, 0.f, 0.f, 0.f};
    #pragma unroll
    for (int i = 0; i < 25; ++i) {
        size_t idx = zbase + (size_t)i * 256;
        if (idx < (size_t)zTotal4) __builtin_nontemporal_store(z4, &outv[idx]);
    }

    // counted wait: 16 oldest (all loads) done; <=25 stores stay in flight
    asm volatile("s_waitcnt vmcnt(25)" ::: "memory");
    __builtin_amdgcn_s_barrier();

    // zero batch B: 25 more, fire-and-forget (never drained inside the kernel)
    #pragma unroll
    for (int i = 25; i < 50; ++i) {
        size_t idx = zbase + (size_t)i * 256;
        if (idx < (size_t)zTotal4) __builtin_nontemporal_store(z4, &outv[idx]);
    }

    // GEMM: this thread = entity eg, outputs og*4..og*4+3, K=256
    float acc0 = 0.f, acc1 = 0.f, acc2 = 0.f, acc3 = 0.f;
    const int es = eg & 7;
    #pragma unroll 8
    for (int k4 = 0; k4 < 64; ++k4) {
        float4 ev = *(const float4*)&s_emb[eg * DIN + ((k4 ^ es) << 2)];
        float4 w0 = *(const float4*)&s_w[(k4 * 4 + 0) * DOUT + og * 4];
        float4 w1 = *(const float4*)&s_w[(k4 * 4 + 1) * DOUT + og * 4];
        float4 w2 = *(const float4*)&s_w[(k4 * 4 + 2) * DOUT + og * 4];
        float4 w3 = *(const float4*)&s_w[(k4 * 4 + 3) * DOUT + og * 4];
        acc0 += ev.x * w0.x + ev.y * w1.x + ev.z * w2.x + ev.w * w3.x;
        acc1 += ev.x * w0.y + ev.y * w1.y + ev.z * w2.y + ev.w * w3.y;
        acc2 += ev.x * w0.z + ev.y * w1.z + ev.z * w2.z + ev.w * w3.z;
        acc3 += ev.x * w0.w + ev.y * w1.w + ev.z * w2.w + ev.w * w3.w;
    }

    const int ent = eb + eg;
    if (ent < nent) {
        const float4 bv = *(const float4*)&bias[og * 4];
        float4 r;
        r.x = fmaxf(acc0 + bv.x, 0.f);
        r.y = fmaxf(acc1 + bv.y, 0.f);
        r.z = fmaxf(acc2 + bv.z, 0.f);
        r.w = fmaxf(acc3 + bv.w, 0.f);
        *(float4*)&ws[(size_t)ent * DOUT + og * 4] = r;
    }
}

// ---------------- k2: masked scatter-add of proj into the zeroed out
__global__ __launch_bounds__(256)
void k2_scatter(const float* __restrict__ ws,
                const int* __restrict__ ex, const int* __restrict__ ey,
                const int* __restrict__ en, const int* __restrict__ pW,
                float* __restrict__ out, int N, int nent, int HW)
{
    const int idx = blockIdx.x * 256 + threadIdx.x;
    const int ent = idx >> 2;
    if (ent >= nent) return;
    const int b = ent / N, n = ent - b * N;
    if (n >= en[b]) return;
    const int cg = (idx & 3) * 8;
    const float4 v0 = *(const float4*)&ws[(size_t)ent * DOUT + cg];
    const float4 v1 = *(const float4*)&ws[(size_t)ent * DOUT + cg + 4];
    const int x = ex[ent], y = ey[ent];
    const int Wd = *pW;
    float* base = out + ((size_t)b * DOUT + cg) * (size_t)HW + (size_t)y * Wd + x;
    const float v[8] = {v0.x, v0.y, v0.z, v0.w, v1.x, v1.y, v1.z, v1.w};
    #pragma unroll
    for (int j = 0; j < 8; ++j)
        if (v[j] != 0.f) atomicAdd(base + (size_t)j * HW, v[j]);
}

// ---------------- fallback (round-1 structure) if ws is too small
constexpr int FET = 128, FKT = 64, FEP = FKT + 4;
__global__ __launch_bounds__(256)
void enc_fallback(const float* __restrict__ emb, const float* __restrict__ weight,
                  const float* __restrict__ bias, const int* __restrict__ ex,
                  const int* __restrict__ ey, const int* __restrict__ enum_,
                  const int* __restrict__ pW, float* __restrict__ out,
                  int N, int nent, int HW)
{
    __shared__ float s_emb[FET][FEP];
    __shared__ float s_w[FKT * DOUT];
    const int tid = threadIdx.x;
    const int og = tid & 7, eg = tid >> 3;
    const int eb = blockIdx.x * FET;
    float acc[4][4];
    #pragma unroll
    for (int i = 0; i < 4; ++i)
        #pragma unroll
        for (int j = 0; j < 4; ++j) acc[i][j] = 0.f;
    for (int kt = 0; kt < DIN; kt += FKT) {
        const float4* src = reinterpret_cast<const float4*>(weight + (size_t)kt * DOUT);
        float4* dst = reinterpret_cast<float4*>(s_w);
        dst[tid] = src[tid];
        dst[tid + 256] = src[tid + 256];
        #pragma unroll
        for (int r = 0; r < 8; ++r) {
            int f = tid + r * 256, e = f >> 4, kk = (f & 15) << 2;
            int eglob = eb + e; if (eglob >= nent) eglob = nent - 1;
            *reinterpret_cast<float4*>(&s_emb[e][kk]) =
                *reinterpret_cast<const float4*>(emb + (size_t)eglob * DIN + kt + kk);
        }
        __syncthreads();
        #pragma unroll
        for (int k = 0; k < FKT; k += 4) {
            float wv[16];
            #pragma unroll
            for (int kk = 0; kk < 4; ++kk)
                *reinterpret_cast<float4*>(&wv[kk * 4]) =
                    *reinterpret_cast<const float4*>(&s_w[(k + kk) * DOUT + og * 4]);
            #pragma unroll
            for (int i = 0; i < 4; ++i) {
                float ev[4];
                *reinterpret_cast<float4*>(ev) =
                    *reinterpret_cast<const float4*>(&s_emb[eg + i * 32][k]);
                #pragma unroll
                for (int j = 0; j < 4; ++j)
                    acc[i][j] += ev[0] * wv[j] + ev[1] * wv[4 + j]
                               + ev[2] * wv[8 + j] + ev[3] * wv[12 + j];
            }
        }
        __syncthreads();
    }
    const int W = *pW;
    float bv[4];
    *reinterpret_cast<float4*>(bv) = *reinterpret_cast<const float4*>(bias + og * 4);
    #pragma unroll
    for (int i = 0; i < 4; ++i) {
        int ent = eb + eg + i * 32;
        if (ent >= nent) continue;
        int b = ent / N, n = ent - b * N;
        if (n >= enum_[b]) continue;
        int x = ex[ent], y = ey[ent];
        float* dst2 = out + ((size_t)b * DOUT + og * 4) * (size_t)HW + (size_t)y * W + x;
        #pragma unroll
        for (int j = 0; j < 4; ++j) {
            float v = fmaxf(acc[i][j] + bv[j], 0.f);
            if (v != 0.f) atomicAdd(dst2 + (size_t)j * HW, v);
        }
    }
}

extern "C" void kernel_launch(void* const* d_in, const int* in_sizes, int n_in,
                              void* d_out, int out_size, void* d_ws, size_t ws_size,
                              hipStream_t stream) {
    const float* emb    = (const float*)d_in[0];
    const float* weight = (const float*)d_in[1];
    const float* bias   = (const float*)d_in[2];
    const int*   ex     = (const int*)d_in[3];
    const int*   ey     = (const int*)d_in[4];
    const int*   en     = (const int*)d_in[5];
    const int*   pW     = (const int*)d_in[7];
    float*       out    = (float*)d_out;

    const int nent = in_sizes[3];                 // B*N
    const int B    = in_sizes[5];
    const int N    = nent / B;
    const int HW   = (int)((size_t)out_size / ((size_t)B * DOUT));
    const int zTotal4 = out_size / 4;

    const size_t ws_need = (size_t)nent * DOUT * sizeof(float);
    const int blocks1 = (nent + ET - 1) / ET;
    const bool fits = (ws_size >= ws_need) && ((size_t)blocks1 * Z4 * 256 >= (size_t)zTotal4);

    if (fits) {
        k1_zero_gemm<<<blocks1, 256, 0, stream>>>(emb, weight, bias, out,
                                                  (float*)d_ws, nent, zTotal4);
        const int blocks2 = (nent * 4 + 255) / 256;
        k2_scatter<<<blocks2, 256, 0, stream>>>((const float*)d_ws, ex, ey, en, pW,
                                                out, N, nent, HW);
    } else {
        (void)hipMemsetAsync(d_out, 0, (size_t)out_size * sizeof(float), stream);
        const int blocks = (nent + FET - 1) / FET;
        enc_fallback<<<blocks, 256, 0, stream>>>(emb, weight, bias, ex, ey, en, pW,
                                                 out, N, nent, HW);
    }
}

// Round 4
// 65.509 us; speedup vs baseline: 1.0338x; 1.0338x over previous
//
#include <hip/hip_runtime.h>

// D_IN=256, D_OUT=32 fixed by the reference.
constexpr int DIN = 256;
constexpr int DOUT = 32;
constexpr int ET  = 64;       // entities per block
constexpr int KT  = 64;       // k-tile
constexpr int EP  = KT + 4;   // 68-float rows: odd granule stride -> conflict-free

// Block: 256 threads. og = tid&7 (4 output cols each), eg = tid>>3 (0..31).
// Thread computes entities {eb+eg, eb+eg+32} x outputs og*4..og*4+3.
__global__ __launch_bounds__(256)
void enc_fused(const float* __restrict__ emb,
               const float* __restrict__ weight,
               const float* __restrict__ bias,
               const int*   __restrict__ ex,
               const int*   __restrict__ ey,
               const int*   __restrict__ en,
               const int*   __restrict__ pW,
               float*       __restrict__ out,
               int N, int nent, int HW)
{
    __shared__ float s_emb[ET][EP];    // 64 x 68 x 4B = 17.4 KB
    __shared__ float s_w[KT * DOUT];   // 8 KB

    const int tid = threadIdx.x;
    const int og  = tid & 7;
    const int eg  = tid >> 3;
    const int eb  = blockIdx.x * ET;

    float4 pe[4];   // emb tile prefetch: 4 float4/thread (64x64 floats)
    float4 pw[2];   // w tile prefetch:   2 float4/thread (64x32 floats)

    // ---- prefetch tile 0
    #pragma unroll
    for (int r = 0; r < 4; ++r) {
        int f = (r << 8) + tid;                 // float4 idx in tile
        int row = f >> 4, col = (f & 15) << 2;
        int e = eb + row; if (e >= nent) e = nent - 1;
        pe[r] = *(const float4*)&emb[(size_t)e * DIN + col];
    }
    #pragma unroll
    for (int r = 0; r < 2; ++r) {
        int f = (r << 8) + tid;
        pw[r] = *(const float4*)&weight[(size_t)(f << 2)];
    }

    float acc0x=0.f,acc0y=0.f,acc0z=0.f,acc0w=0.f;
    float acc1x=0.f,acc1y=0.f,acc1z=0.f,acc1w=0.f;

    for (int t = 0; t < 4; ++t) {
        // ---- store staged regs -> LDS
        #pragma unroll
        for (int r = 0; r < 4; ++r) {
            int f = (r << 8) + tid;
            *(float4*)&s_emb[f >> 4][(f & 15) << 2] = pe[r];
        }
        #pragma unroll
        for (int r = 0; r < 2; ++r) {
            int f = (r << 8) + tid;
            *(float4*)&s_w[f << 2] = pw[r];
        }
        __syncthreads();

        // ---- issue next tile's global loads (latency hides under compute)
        if (t < 3) {
            const int kt = (t + 1) * KT;
            #pragma unroll
            for (int r = 0; r < 4; ++r) {
                int f = (r << 8) + tid;
                int row = f >> 4, col = (f & 15) << 2;
                int e = eb + row; if (e >= nent) e = nent - 1;
                pe[r] = *(const float4*)&emb[(size_t)e * DIN + kt + col];
            }
            #pragma unroll
            for (int r = 0; r < 2; ++r) {
                int f = (r << 8) + tid;
                pw[r] = *(const float4*)&weight[(size_t)kt * DOUT + (f << 2)];
            }
        }

        // ---- compute this tile (all LDS reads are 8-addr broadcasts, conflict-free)
        #pragma unroll
        for (int k = 0; k < KT; k += 4) {
            float4 e0 = *(const float4*)&s_emb[eg][k];
            float4 e1 = *(const float4*)&s_emb[eg + 32][k];
            float4 w0 = *(const float4*)&s_w[(k + 0) * DOUT + og * 4];
            float4 w1 = *(const float4*)&s_w[(k + 1) * DOUT + og * 4];
            float4 w2 = *(const float4*)&s_w[(k + 2) * DOUT + og * 4];
            float4 w3 = *(const float4*)&s_w[(k + 3) * DOUT + og * 4];
            acc0x += e0.x*w0.x + e0.y*w1.x + e0.z*w2.x + e0.w*w3.x;
            acc0y += e0.x*w0.y + e0.y*w1.y + e0.z*w2.y + e0.w*w3.y;
            acc0z += e0.x*w0.z + e0.y*w1.z + e0.z*w2.z + e0.w*w3.z;
            acc0w += e0.x*w0.w + e0.y*w1.w + e0.z*w2.w + e0.w*w3.w;
            acc1x += e1.x*w0.x + e1.y*w1.x + e1.z*w2.x + e1.w*w3.x;
            acc1y += e1.x*w0.y + e1.y*w1.y + e1.z*w2.y + e1.w*w3.y;
            acc1z += e1.x*w0.z + e1.y*w1.z + e1.z*w2.z + e1.w*w3.z;
            acc1w += e1.x*w0.w + e1.y*w1.w + e1.z*w2.w + e1.w*w3.w;
        }
        __syncthreads();
    }

    // ---- epilogue: bias + relu + mask + scatter-add
    const int W = *pW;
    const float4 bv = *(const float4*)&bias[og * 4];
    float a[2][4] = {{acc0x,acc0y,acc0z,acc0w},{acc1x,acc1y,acc1z,acc1w}};

    #pragma unroll
    for (int i = 0; i < 2; ++i) {
        int ent = eb + eg + i * 32;
        if (ent >= nent) continue;
        int b = ent / N, n = ent - b * N;
        if (n >= en[b]) continue;                 // masked (padded) entity
        float* dst = out + ((size_t)b * DOUT + og * 4) * (size_t)HW
                         + (size_t)ey[ent] * W + ex[ent];
        float v0 = fmaxf(a[i][0] + bv.x, 0.f);
        float v1 = fmaxf(a[i][1] + bv.y, 0.f);
        float v2 = fmaxf(a[i][2] + bv.z, 0.f);
        float v3 = fmaxf(a[i][3] + bv.w, 0.f);
        if (v0 != 0.f) atomicAdd(dst + 0 * (size_t)HW, v0);
        if (v1 != 0.f) atomicAdd(dst + 1 * (size_t)HW, v1);
        if (v2 != 0.f) atomicAdd(dst + 2 * (size_t)HW, v2);
        if (v3 != 0.f) atomicAdd(dst + 3 * (size_t)HW, v3);
    }
}

extern "C" void kernel_launch(void* const* d_in, const int* in_sizes, int n_in,
                              void* d_out, int out_size, void* d_ws, size_t ws_size,
                              hipStream_t stream) {
    const float* emb    = (const float*)d_in[0];
    const float* weight = (const float*)d_in[1];
    const float* bias   = (const float*)d_in[2];
    const int*   ex     = (const int*)d_in[3];
    const int*   ey     = (const int*)d_in[4];
    const int*   en     = (const int*)d_in[5];
    const int*   pW     = (const int*)d_in[7];
    float*       out    = (float*)d_out;

    const int nent = in_sizes[3];          // B*N
    const int B    = in_sizes[5];
    const int N    = nent / B;
    const int HW   = (int)((size_t)out_size / ((size_t)B * DOUT));

    // Output is a scatter-add target and the harness doesn't re-poison between
    // replays: full zero every call.
    (void)hipMemsetAsync(d_out, 0, (size_t)out_size * sizeof(float), stream);

    const int blocks = (nent + ET - 1) / ET;
    enc_fused<<<blocks, 256, 0, stream>>>(emb, weight, bias, ex, ey, en, pW,
                                          out, N, nent, HW);
}